// Round 9
// baseline (199.482 us; speedup 1.0000x reference)
//
#include <hip/hip_runtime.h>
#include <cstdint>
#include <cstddef>

// MHA: B=2, H=16, S=2048, D=1024, dk=64. fp32 in/out, bf16 MFMA compute.
#define SEQ   2048
#define NH    16
#define DK    64
#define DM    1024
#define MTOT  4096
#define QSCALE (0.125f * 1.44269504088896f)   // 1/sqrt(dk) * log2(e), folded into Q

typedef __attribute__((ext_vector_type(8))) short           short8;
typedef __attribute__((ext_vector_type(8))) unsigned short  ushort8;
typedef __attribute__((ext_vector_type(4))) unsigned short  ushort4v;
typedef __attribute__((ext_vector_type(2))) unsigned int    uint2v;
typedef __attribute__((ext_vector_type(4))) float           float4v;
typedef unsigned short u16;
typedef unsigned int   u32;

__device__ inline float4v mfma16(short8 a, short8 b, float4v c) {
    return __builtin_amdgcn_mfma_f32_16x16x32_bf16(a, b, c, 0, 0, 0);
}
__device__ inline u16 f2bf(float f) {              // fp32->bf16 RNE
    u32 u = __float_as_uint(f);
    u += 0x7fffu + ((u >> 16) & 1u);
    return (u16)(u >> 16);
}
// pack 2 fp32 -> 2 bf16 (round-half-up) in 3 VALU (HW-verified R2..R6)
__device__ inline u32 pkbf(float a, float b) {
    u32 ua = __float_as_uint(a) + 0x8000u;
    u32 ub = __float_as_uint(b) + 0x8000u;
    return __builtin_amdgcn_perm(ub, ua, 0x07060302);
}
__device__ inline void gld16(const void* g, void* lds) {  // async global->LDS, 16B/lane
    __builtin_amdgcn_global_load_lds(
        (const __attribute__((address_space(1))) u32*)g,
        (__attribute__((address_space(3))) u32*)lds, 16, 0, 0);
}
#define LGKM_FENCE() asm volatile("s_waitcnt lgkmcnt(0)" ::: "memory")

// ---------------------------------------------------------------------------
__global__ __launch_bounds__(256)
void convert_x(const float* __restrict__ x, u16* __restrict__ xb)
{
    const int i = blockIdx.x * 256 + threadIdx.x;
    const float4v a = ((const float4v*)x)[2 * i];
    const float4v b = ((const float4v*)x)[2 * i + 1];
    ushort8 o;
    #pragma unroll
    for (int j = 0; j < 4; j++) { o[j] = f2bf(a[j]); o[4 + j] = f2bf(b[j]); }
    ((ushort8*)xb)[i] = o;
}

// ---------------------------------------------------------------------------
__global__ __launch_bounds__(256)
void transpose_w(const float* __restrict__ W0, const float* __restrict__ W1,
                 const float* __restrict__ W2, const float* __restrict__ W3,
                 u16* __restrict__ T0, u16* __restrict__ T1,
                 u16* __restrict__ T2, u16* __restrict__ T3)
{
    __shared__ u16 t[64][68];
    const float* W; u16* T;
    switch (blockIdx.z) {
        case 0: W = W0; T = T0; break;
        case 1: W = W1; T = T1; break;
        case 2: W = W2; T = T2; break;
        default: W = W3; T = T3; break;
    }
    const int n0 = blockIdx.x * 64, k0 = blockIdx.y * 64;
    const int r  = threadIdx.x >> 4;
    const int c4 = (threadIdx.x & 15) * 4;
    #pragma unroll
    for (int i = 0; i < 4; i++) {
        float4v v = *(const float4v*)&W[(size_t)(k0 + r + i * 16) * DM + n0 + c4];
        #pragma unroll
        for (int j = 0; j < 4; j++) t[r + i * 16][c4 + j] = f2bf(v[j]);
    }
    __syncthreads();
    #pragma unroll
    for (int i = 0; i < 4; i++) {
        const int rr = r + i * 16;
        ushort4v o;
        #pragma unroll
        for (int j = 0; j < 4; j++) o[j] = t[c4 + j][rr];
        *(ushort4v*)&T[(size_t)(n0 + rr) * DM + k0 + c4] = o;
    }
}

// ---------------------------------------------------------------------------
// GEMM: C[M,N] = A[M,1024] @ WT[N,1024]^T + bias   (m97 pattern)
// <TM,TN,MODE>. MODE 1 (TM=TN=128 only): fused QKV, N=3072: Q,K split-head
// [B,H,S,dk] bf16 (Q scaled); V transposed [B,H,dk,S] bf16.
// MODE 0: fp32 [M][N..] out (O-proj). TN=64 variant doubles grid for
// occupancy: (16,64)=1024 blocks = 4/CU x 4 waves = 16 waves/CU.
// ---------------------------------------------------------------------------
template<int TM, int TN, int MODE>
__global__ __launch_bounds__(TM * 4)
void gemm_bt(const u16* __restrict__ A, const u16* __restrict__ WT,
             const float* __restrict__ bq, const float* __restrict__ bk,
             const float* __restrict__ bv,
             void* __restrict__ out0, u16* __restrict__ outK, u16* __restrict__ outV)
{
    constexpr int NT = TM * 4;          // threads (4 waves per 64 rows of TM)
    constexpr int NI = TN / 64;         // n-subtiles per wave (128->2, 64->1)
    __shared__ u16 Al[TM][64];
    __shared__ u16 Bl[TN][64];
    const int tid  = threadIdx.x;
    const int lane = tid & 63, w = tid >> 6;
    const int quad = lane >> 4, l16 = lane & 15;
    const int n0 = blockIdx.x * TN, m0 = blockIdx.y * TM;
    const int wm = (TM == 128) ? (w >> 2) * 64 : 0;
    const int wn = (TM == 128) ? (w & 3) * 32 : w * (TN / 4);

    float4v acc[4][NI] = {};

    for (int k0 = 0; k0 < DM; k0 += 64) {
        __syncthreads();
        #pragma unroll
        for (int j = 0; j < TM * 8 / NT; j++) {
            const int c = j * NT + tid;
            const int row = c >> 3, kc = c & 7;
            gld16(A + (size_t)(m0 + row) * DM + k0 + ((kc ^ (row & 7)) * 8),
                  &Al[0][0] + (size_t)(j * NT + w * 64) * 8);
        }
        #pragma unroll
        for (int j = 0; j < TN * 8 / NT; j++) {
            const int c = j * NT + tid;
            const int row = c >> 3, kc = c & 7;
            gld16(WT + (size_t)(n0 + row) * DM + k0 + ((kc ^ (row & 7)) * 8),
                  &Bl[0][0] + (size_t)(j * NT + w * 64) * 8);
        }
        __syncthreads();
        #pragma unroll
        for (int u = 0; u < 2; u++) {
            short8 af[4], bf[NI];
            #pragma unroll
            for (int mi = 0; mi < 4; mi++) {
                const int row = wm + mi * 16 + l16;
                af[mi] = *(const short8*)&Al[row][((4 * u + quad) ^ (row & 7)) * 8];
            }
            #pragma unroll
            for (int ni = 0; ni < NI; ni++) {
                const int row = wn + ni * 16 + l16;
                bf[ni] = *(const short8*)&Bl[row][((4 * u + quad) ^ (row & 7)) * 8];
            }
            #pragma unroll
            for (int mi = 0; mi < 4; mi++)
                #pragma unroll
                for (int ni = 0; ni < NI; ni++)
                    acc[mi][ni] = mfma16(af[mi], bf[ni], acc[mi][ni]);
        }
    }

    if constexpr (MODE == 0) {
        float* out = (float*)out0;
        #pragma unroll
        for (int ni = 0; ni < NI; ni++) {
            const int col = n0 + wn + ni * 16 + l16;
            const float bb = bq[col];
            #pragma unroll
            for (int mi = 0; mi < 4; mi++)
                #pragma unroll
                for (int r = 0; r < 4; r++) {
                    const int row = m0 + wm + mi * 16 + quad * 4 + r;
                    out[(size_t)row * DM + col] = acc[mi][ni][r] + bb;
                }
        }
    } else {
        const int seg = n0 >> 10;                     // 0=Q 1=K 2=V (uniform/block)
        u16* outp = (seg == 0) ? (u16*)out0 : (seg == 1 ? outK : outV);
        const float* bias = (seg == 0) ? bq : (seg == 1 ? bk : bv);
        const float scl = (seg == 0) ? QSCALE : 1.0f;
        if (seg < 2) {                                // Q/K: [B,H,S,dk]
            #pragma unroll
            for (int ni = 0; ni < NI; ni++) {
                const int col = (n0 & 1023) + wn + ni * 16 + l16;
                const float bb = bias[col];
                const int h = col >> 6, d = col & 63;
                #pragma unroll
                for (int mi = 0; mi < 4; mi++)
                    #pragma unroll
                    for (int r = 0; r < 4; r++) {
                        const int row = m0 + wm + mi * 16 + quad * 4 + r;
                        const int b = row >> 11, s = row & (SEQ - 1);
                        outp[(((size_t)(b * NH + h) * SEQ + s) << 6) + d] =
                            f2bf((acc[mi][ni][r] + bb) * scl);
                    }
            }
        } else {                                      // V: transposed [B,H,dk,S]
            #pragma unroll
            for (int ni = 0; ni < NI; ni++) {
                const int col = (n0 & 1023) + wn + ni * 16 + l16;
                const float bb = bias[col];
                const int h = col >> 6, d = col & 63;
                #pragma unroll
                for (int mi = 0; mi < 4; mi++) {
                    const int row0 = m0 + wm + mi * 16 + quad * 4;  // r contiguous in s
                    const int b = row0 >> 11, s = row0 & (SEQ - 1);
                    uint2v pv;
                    pv[0] = pkbf(acc[mi][ni][0] + bb, acc[mi][ni][1] + bb);
                    pv[1] = pkbf(acc[mi][ni][2] + bb, acc[mi][ni][3] + bb);
                    *(uint2v*)&outp[(((size_t)((b * NH + h) * DK + d)) << 11) + s] = pv;
                }
            }
        }
    }
}

// ---------------------------------------------------------------------------
// Flash attention v4 (R6, HW-PROVEN — restored byte-identical after the R7/R8
// 16-wave redesign failed correctness twice; that design is quarantined).
// 512 thr / 8 waves: waves 0-3 kv[0,1024), waves 4-7 kv[1024,2048); each wave
// 32 q (g=2 -> every K/V frag read feeds 2 MFMAs). kv tiles 32, dbuf gld16.
// No-max streaming softmax (|s*log2e| <= ~22; exp2 safe) -> kv-half partials
// exactly additive -> deterministic in-LDS combine at end.
// NOTE: Pl row pitch (40 u16 = 80 B) MUST stay a multiple of 16 B — the pf
// ds_read_b128 at l16*pitch + quad*16 goes misaligned otherwise (R7 failure).
// ---------------------------------------------------------------------------
__global__ __launch_bounds__(512, 4)
void attn_kernel(const u16* __restrict__ Q, const u16* __restrict__ K,
                 const u16* __restrict__ VT, u16* __restrict__ Ctx)
{
    __shared__ u16 Kl[2][2][32][64];   // [buf][kvhalf][kv][d], xor-swizzled chunks
    __shared__ u16 Vl[2][2][64][32];   // [buf][kvhalf][d][kv], xor-swizzled chunks
    __shared__ u16 Pl[8][32][40];      // per-wave P[q][kv] (pad 40 -> 80B rows)
    __shared__ float Xl[4][64][17];    // cross-group combine (pad 17: conflict-free)

    const int tid  = threadIdx.x;
    const int lane = tid & 63, w = tid >> 6;
    const int wq = w & 3, wgrp = w >> 2;
    const int quad = lane >> 4, l16 = lane & 15;
    const int qt = blockIdx.x;         // 0..15 (128 q per block)
    const int bh = blockIdx.y;         // 0..31
    const size_t head = (size_t)bh * SEQ * DK;

    // Q B-frags for this wave's 32 q (two groups of 16): n=q=l16, k=quad*8(+32)
    short8 qf[2][2];
    #pragma unroll
    for (int g = 0; g < 2; g++) {
        const size_t qrow = head + (size_t)(qt * 128 + wq * 32 + g * 16 + l16) * DK;
        qf[g][0] = *(const short8*)(Q + qrow + quad * 8);
        qf[g][1] = *(const short8*)(Q + qrow + 32 + quad * 8);
    }

    float4v acc[2][4] = {};            // O^T[d = t*16+quad*4+r][q = g*16+l16]
    float l_part[2] = {0.f, 0.f};

    // staging geometry: 1024 chunks (16B) per iter = 1 K + 1 V gld16 per thread
    const int sh = tid >> 8;                         // kv half staged by this thread
    const int rK = (tid >> 3) & 31, cK = tid & 7;    // K: [half][32 kv][8 chunks]
    const int dV = (tid >> 2) & 63, cV = tid & 3;    // V: [half][64 d][4 chunks]
    const int sVk = (dV & 3) ^ ((dV >> 2) & 3);
    const u16* const Kg = K  + head + (size_t)(sh * 1024 + rK) * DK + (cK ^ (rK & 7)) * 8;
    const u16* const Vg = VT + head + (size_t)dV * SEQ + sh * 1024 + (cV ^ sVk) * 8;
    u16* const Kdst = &Kl[0][0][0][0] + tid * 8;     // + buf*4096 (u16)
    u16* const Vdst = &Vl[0][0][0][0] + tid * 8;

    gld16(Kg, Kdst);
    gld16(Vg, Vdst);

    for (int it = 0; it < 32; it++) {
        const int cur = it & 1;
        __syncthreads();                       // drains gld for buf[cur]
        if (it + 1 < 32) {
            gld16(Kg + (size_t)(it + 1) * 32 * DK, Kdst + (cur ^ 1) * 4096);
            gld16(Vg + (size_t)(it + 1) * 32,      Vdst + (cur ^ 1) * 4096);
        }

        // S^T (32 kv x 32 q) + streaming softmax + P -> LDS [q][kv]
        #pragma unroll
        for (int t = 0; t < 2; t++) {
            const int row = t * 16 + l16;
            const short8 kf0 = *(const short8*)&Kl[cur][wgrp][row][(quad ^ (row & 7)) * 8];
            const short8 kf1 = *(const short8*)&Kl[cur][wgrp][row][((4 + quad) ^ (row & 7)) * 8];
            #pragma unroll
            for (int g = 0; g < 2; g++) {
                float4v z = {};
                z = mfma16(kf0, qf[g][0], z);
                z = mfma16(kf1, qf[g][1], z);
                const float p0 = exp2f(z[0]), p1 = exp2f(z[1]);
                const float p2 = exp2f(z[2]), p3 = exp2f(z[3]);
                l_part[g] += (p0 + p1) + (p2 + p3);
                uint2v pk; pk[0] = pkbf(p0, p1); pk[1] = pkbf(p2, p3);
                *(uint2v*)&Pl[w][g * 16 + l16][t * 16 + quad * 4] = pk;
            }
        }
        LGKM_FENCE();                          // cross-lane P write -> read
        short8 pf[2];
        pf[0] = *(const short8*)&Pl[w][l16][quad * 8];
        pf[1] = *(const short8*)&Pl[w][16 + l16][quad * 8];

        // O^T += V^T · P^T  (each vf read feeds 2 MFMAs)
        #pragma unroll
        for (int t = 0; t < 4; t++) {
            const int d = t * 16 + l16;
            const short8 vf =
                *(const short8*)&Vl[cur][wgrp][d][(quad ^ ((d & 3) ^ ((d >> 2) & 3))) * 8];
            acc[0][t] = mfma16(vf, pf[0], acc[0][t]);
            acc[1][t] = mfma16(vf, pf[1], acc[1][t]);
        }
    }

    // per-wave l reduction (once)
    #pragma unroll
    for (int g = 0; g < 2; g++) {
        l_part[g] += __shfl_xor(l_part[g], 16);
        l_part[g] += __shfl_xor(l_part[g], 32);
    }

    // deterministic cross-group combine (group1 -> group0), 2 passes over t
    float ltot[2];
    #pragma unroll
    for (int p = 0; p < 2; p++) {
        __syncthreads();
        if (wgrp == 1) {
            #pragma unroll
            for (int g = 0; g < 2; g++)
                #pragma unroll
                for (int tt = 0; tt < 2; tt++)
                    #pragma unroll
                    for (int r = 0; r < 4; r++)
                        Xl[wq][lane][g * 8 + tt * 4 + r] = acc[g][2 * p + tt][r];
            Xl[wq][lane][16] = l_part[p];
        }
        __syncthreads();
        if (wgrp == 0) {
            #pragma unroll
            for (int g = 0; g < 2; g++)
                #pragma unroll
                for (int tt = 0; tt < 2; tt++)
                    #pragma unroll
                    for (int r = 0; r < 4; r++)
                        acc[g][2 * p + tt][r] += Xl[wq][lane][g * 8 + tt * 4 + r];
            ltot[p] = l_part[p] + Xl[wq][lane][16];
        }
    }

    // epilogue (group0 waves): normalize + packed 8B stores
    if (wgrp == 0) {
        const int b = bh >> 4, h = bh & 15;
        #pragma unroll
        for (int g = 0; g < 2; g++) {
            const float rl = 1.0f / ltot[g];
            const int s = qt * 128 + wq * 32 + g * 16 + l16;
            u16* dst = Ctx + (size_t)(b * SEQ + s) * DM + h * 64 + quad * 4;
            #pragma unroll
            for (int t = 0; t < 4; t++) {
                uint2v ov;
                ov[0] = pkbf(acc[g][t][0] * rl, acc[g][t][1] * rl);
                ov[1] = pkbf(acc[g][t][2] * rl, acc[g][t][3] * rl);
                *(uint2v*)&dst[t * 16] = ov;
            }
        }
    }
}

// ---------------------------------------------------------------------------
extern "C" void kernel_launch(void* const* d_in, const int* in_sizes, int n_in,
                              void* d_out, int out_size, void* d_ws, size_t ws_size,
                              hipStream_t stream)
{
    const float* x   = (const float*)d_in[0];
    const float* W_q = (const float*)d_in[1];
    const float* b_q = (const float*)d_in[2];
    const float* W_k = (const float*)d_in[3];
    const float* b_k = (const float*)d_in[4];
    const float* W_v = (const float*)d_in[5];
    const float* b_v = (const float*)d_in[6];
    const float* W_o = (const float*)d_in[7];
    const float* b_o = (const float*)d_in[8];

    // ws (24 MB): [xb 8 | WTqkv 6 | WTo 2 | VT 8]; Cb aliases xb (dead then).
    // d_out (16 MB fp32) hosts Qb+Kb bf16 until attn consumes them.
    u16* xb  = (u16*)d_ws;
    u16* WT  = xb + (size_t)MTOT * DM;
    u16* WTo = WT + (size_t)3 * DM * DM;
    u16* VTb = WTo + (size_t)DM * DM;
    u16* Cb  = xb;
    u16* Qb  = (u16*)d_out;
    u16* Kb  = Qb + (size_t)MTOT * DM;

    convert_x<<<2048, 256, 0, stream>>>(x, xb);
    transpose_w<<<dim3(16, 16, 4), 256, 0, stream>>>(
        W_q, W_k, W_v, W_o, WT, WT + (size_t)DM * DM, WT + (size_t)2 * DM * DM, WTo);
    gemm_bt<128, 128, 1><<<dim3(24, 32), 512, 0, stream>>>(xb, WT, b_q, b_k, b_v,
                                                           Qb, Kb, VTb);
    attn_kernel<<<dim3(SEQ / 128, 2 * NH), 512, 0, stream>>>(Qb, Kb, VTb, Cb);
    gemm_bt<64, 64, 0><<<dim3(16, 64), 256, 0, stream>>>(Cb, WTo, b_o, nullptr, nullptr,
                                                         (float*)d_out, nullptr, nullptr);
}